// Round 1
// baseline (612.324 us; speedup 1.0000x reference)
//
#include <hip/hip_runtime.h>
#include <hip/hip_bf16.h>

// MixedDimTableBatchedEmbeddingBags
// 8 tables, 250k rows each, dims {16,32,64,128,16,32,64,128}, B=8192, L=32.
// out[b, colOff_t + d] = sum_l weights[woff_t + idx[t,b,l]*dim_t + d] * psw[t,b,l]
//
// Mapping: one thread per output float4. g = b*120 + c, c in [0,120) indexes
// the float4 column groups of the 480-wide output row. Writes are perfectly
// coalesced (((float4*)out)[g]). Threads within a bag sub-group (4..32 lanes)
// broadcast-load the same 32 indices / per-sample weights (L1-served) and
// gather contiguous float4 segments of each embedding row.

#define T_TABLES 8
#define BATCH    8192
#define BAG_L    32
#define GROUPS_PER_ROW 120   // 480 floats / 4
#define TOTAL_GROUPS (BATCH * GROUPS_PER_ROW)  // 983040

__constant__ int   c_bound[9] = {0, 4, 12, 28, 60, 64, 72, 88, 120};
__constant__ int   c_dim[8]   = {16, 32, 64, 128, 16, 32, 64, 128};
__constant__ unsigned c_woff[8] = {0u, 4000000u, 12000000u, 28000000u,
                                   60000000u, 64000000u, 72000000u, 88000000u};

__global__ __launch_bounds__(256) void emb_bags_kernel(
    const float* __restrict__ weights,
    const int*   __restrict__ indices,
    const float* __restrict__ psw,
    float*       __restrict__ out)
{
    const int g = blockIdx.x * blockDim.x + threadIdx.x;  // < TOTAL_GROUPS (exact)
    const int b = g / GROUPS_PER_ROW;
    const int c = g - b * GROUPS_PER_ROW;

    // Which table does column-group c belong to? (branchless)
    const int t = (c >= 4) + (c >= 12) + (c >= 28) + (c >= 60)
                + (c >= 64) + (c >= 72) + (c >= 88);

    const int      dim   = c_dim[t];
    const unsigned wbase = c_woff[t] + (unsigned)(c - c_bound[t]) * 4u;
    const int      ibase = (t * BATCH + b) * BAG_L;

    const int*   idx = indices + ibase;
    const float* pw  = psw + ibase;

    float4 acc = make_float4(0.f, 0.f, 0.f, 0.f);
#pragma unroll 8
    for (int l = 0; l < BAG_L; ++l) {
        const unsigned row = (unsigned)idx[l];
        const float    w   = pw[l];
        const float4 v = *(const float4*)(weights + (size_t)(wbase + row * (unsigned)dim));
        acc.x += v.x * w;
        acc.y += v.y * w;
        acc.z += v.z * w;
        acc.w += v.w * w;
    }
    ((float4*)out)[g] = acc;
}

extern "C" void kernel_launch(void* const* d_in, const int* in_sizes, int n_in,
                              void* d_out, int out_size, void* d_ws, size_t ws_size,
                              hipStream_t stream) {
    const float* weights = (const float*)d_in[0];
    const int*   indices = (const int*)d_in[1];
    // d_in[2] = offsets (uniform stride, unused)
    const float* psw     = (const float*)d_in[3];
    float*       out     = (float*)d_out;

    const int block = 256;
    const int grid  = TOTAL_GROUPS / block;  // 3840
    emb_bags_kernel<<<grid, block, 0, stream>>>(weights, indices, psw, out);
}